// Round 7
// baseline (172.059 us; speedup 1.0000x reference)
//
#include <hip/hip_runtime.h>

// Problem: BATCH=64, NFILT=512, T=1024, FFT over first 512 samples, 257 bins.
//   bc = (fc/Q)*0.5*sqrt(2pi)/FS ; n = t+1
//   y[b,f,t] = exp(-(bc*n)^2) * cos(2pi*fc/FS*n)
//   maxsq[f] = max_{b,k} |DFT_512(y[b,f,0:512])[k]|^2
//   out[b,f,t] = y[b,f,1023-t] * rsqrt(maxsq[f])
//
// R7: LDS-free k_maxfft. Lanes = time (lane l holds samples n=l+1+64r in
// registers), 5 consecutive bins per group via complex-phasor recurrence
// (per-64-step rotator e^{-i*pi*k/4}, wave-uniform). Groups cover
// [kci-2, kci+2]; in the main/image merge zone (image at 512-kc within
// ~2.5 sigma, sigma = 163*bc bins) the peak migrates toward bin 256, so
// coverage extends gap-free to 256. Bins outside [0,256] alias valid
// magnitudes (|X[-k]|=|X[k]|=|X[512-k]|) -> no clamping needed.
// Reductions via gfx9 DPP (row_shr/row_bcast) -> VALU pipe, zero DS ops.

#define BCOEF_K 7.8332133582218756e-05f  // 0.5*sqrt(2*pi)/16000
#define INV_FS  6.25e-05f                // 1/16000
#define TWO_PI  6.28318530717958647692f

typedef float vf4 __attribute__((ext_vector_type(4)));  // nt-store compatible

// cos(2*pi * n * fcn), phase reduced in revolutions -> native v_cos.
__device__ __forceinline__ float fast_carrier(float fcn, float n) {
  float rev = fcn * n;
  float fr  = rev - floorf(rev);
  return __cosf(TWO_PI * fr);
}
__device__ __forceinline__ float fast_env(float x) { return __expf(-x * x); }

// Wave64 sum via DPP: row_shr 1/2/4/8 (row sums in lanes 15/31/47/63),
// row_bcast15 (rows 1,3), row_bcast31 (rows 2,3) -> total in lane 63,
// broadcast back uniform via readlane. VALU-only; old=0 is the add identity.
#define DPP_STEP(x, ctrl, rmask)                                              \
  x += __int_as_float(__builtin_amdgcn_update_dpp(                            \
      0, __float_as_int(x), ctrl, rmask, 0xf, false))

__device__ __forceinline__ float wave_sum(float x) {
  DPP_STEP(x, 0x111, 0xf);   // row_shr:1
  DPP_STEP(x, 0x112, 0xf);   // row_shr:2
  DPP_STEP(x, 0x114, 0xf);   // row_shr:4
  DPP_STEP(x, 0x118, 0xf);   // row_shr:8
  DPP_STEP(x, 0x142, 0xa);   // row_bcast:15 -> rows 1,3
  DPP_STEP(x, 0x143, 0xc);   // row_bcast:31 -> rows 2,3
  return __int_as_float(__builtin_amdgcn_readlane(__float_as_int(x), 63));
}

// ---------------------------------------------------------------------------
// Kernel 1: block = 4 independent waves; wave w owns signal sig = blk*4+w.
// No LDS, no atomics. Result -> ws[f*64 + bb].
// ---------------------------------------------------------------------------
__global__ __launch_bounds__(256) void k_maxfft(const float* __restrict__ Q,
                                                const float* __restrict__ fc,
                                                float* __restrict__ ws) {
  const int tid  = threadIdx.x;
  const int w    = tid >> 6;           // wave 0..3
  const int lane = tid & 63;
  const int sig  = blockIdx.x * 4 + w; // bb*512 + f
  const int f    = sig & 511;
  const int bb   = sig >> 9;

  const float fcv = fc[f];
  const float q   = Q[bb * 512 + f];
  const float bc  = (fcv / q) * BCOEF_K;
  const float fcn = fcv * INV_FS;

  // envelope < e^-16 beyond nstar = 4/bc; R = 64-sample groups needed (1..8)
  const float nstar = 4.0f / bc;
  const int   R = (nstar >= 505.0f) ? 8 : (((int)nstar + 2 + 63) >> 6);

  // --- generate samples n = lane+1+64r into registers (wave-uniform R) ---
  const float n0 = (float)(lane + 1);
  float yv[8];
  #pragma unroll
  for (int r = 0; r < 8; ++r) {
    if (r < R) {
      const float n = n0 + (float)(r << 6);
      yv[r] = fast_env(bc * n) * fast_carrier(fcn, n);
    }
  }

  // --- candidate bin range (all wave-uniform) ---
  const int kci = (int)(fcn * 512.0f + 0.5f);
  const int lo  = kci - 2;
  int       hi  = kci + 2;
  // merge zone: image lobe at 512-kc within ~2.5 sigma of main lobe
  if (407.0f * bc > (float)(512 - 2 * kci)) hi = 256;

  float mx = 0.0f;
  for (int c = lo; c <= hi; c += 5) {  // consecutive 5-bin groups, no gaps
    // initial phasors p_j = e^{-i*2pi*(c+j)*(lane+1)/512}, j = 0..4.
    // All phase products are integers*2^-9 <= 2^24 -> exact reduction.
    const float lrev = n0 * (1.0f / 512.0f);
    const float revc = (float)c * lrev;
    const float ac   = TWO_PI * (revc - floorf(revc));
    const float ad   = TWO_PI * lrev;            // per-bin step, per-lane
    const float dre  = __cosf(ad), dim = -__sinf(ad);
    float pre[5], pim[5];
    pre[0] = __cosf(ac); pim[0] = -__sinf(ac);
    #pragma unroll
    for (int j = 1; j < 5; ++j) {
      pre[j] = pre[j-1] * dre - pim[j-1] * dim;
      pim[j] = pre[j-1] * dim + pim[j-1] * dre;
    }
    // per-64-sample rotators E_j = e^{-i*pi*(c+j)/4} (wave-uniform)
    float er[5], ei[5];
    {
      const float rev8 = (float)c * 0.125f;
      const float ae   = TWO_PI * (rev8 - floorf(rev8));
      er[0] = __cosf(ae); ei[0] = -__sinf(ae);
      const float hr = 0.70710678118654752440f;  // cos(pi/4)
      #pragma unroll
      for (int j = 1; j < 5; ++j) {              // multiply by e^{-i*pi/4}
        er[j] = (er[j-1] + ei[j-1]) * hr;
        ei[j] = (ei[j-1] - er[j-1]) * hr;
      }
    }

    float Xre[5] = {0,0,0,0,0}, Xim[5] = {0,0,0,0,0};
    #pragma unroll
    for (int r = 0; r < 8; ++r) {
      if (r < R) {
        const float y = yv[r];
        #pragma unroll
        for (int j = 0; j < 5; ++j) {
          Xre[j] = fmaf(y, pre[j], Xre[j]);
          Xim[j] = fmaf(y, pim[j], Xim[j]);
          const float t = pre[j] * er[j] - pim[j] * ei[j];
          pim[j] = fmaf(pre[j], ei[j], pim[j] * er[j]);
          pre[j] = t;
        }
      }
    }

    #pragma unroll
    for (int j = 0; j < 5; ++j) {
      const float re = wave_sum(Xre[j]);
      const float im = wave_sum(Xim[j]);
      mx = fmaxf(mx, fmaf(re, re, im * im));
    }
  }

  if (lane == 0) ws[f * 64 + bb] = mx;   // per-signal result, no atomic
}

// ---------------------------------------------------------------------------
// Kernel 2: one block per (b,f) row. Each wave loads the 64 per-batch
// results for f, shfl-max -> maxsq; thread tid writes float4 at t0=4*tid,
// n = 1024 - t (flip), scaled by rsqrt(maxsq). Dead tail stores zeros.
// ---------------------------------------------------------------------------
__global__ __launch_bounds__(256) void k_write(const float* __restrict__ Q,
                                               const float* __restrict__ fc,
                                               const float* __restrict__ ws,
                                               float* __restrict__ out) {
  const int blk = blockIdx.x;      // bb*512 + f
  const int f   = blk & 511;
  const int bb  = blk >> 9;
  const int tid = threadIdx.x;

  // max over batch of |X|^2 for this f (64 contiguous floats, L2-hot)
  float mx = ws[f * 64 + (tid & 63)];
  #pragma unroll
  for (int d = 32; d > 0; d >>= 1) mx = fmaxf(mx, __shfl_xor(mx, d));

  const float fcv = fc[f];
  const float q   = Q[bb * 512 + f];
  const float bc  = (fcv / q) * BCOEF_K;
  const float fcn = fcv * INV_FS;
  const float nstar = 4.0f / bc;

  const int t0 = tid * 4;
  vf4 r = {0.0f, 0.0f, 0.0f, 0.0f};
  // quad covers n = 1021-t0 .. 1024-t0; all dead iff smallest n > nstar
  if ((float)(1021 - t0) <= nstar) {
    const float inv = rsqrtf(mx);
    const float n0 = (float)(1024 - t0);
    const float n1 = (float)(1023 - t0);
    const float n2 = (float)(1022 - t0);
    const float n3 = (float)(1021 - t0);
    r.x = fast_env(bc * n0) * fast_carrier(fcn, n0) * inv;
    r.y = fast_env(bc * n1) * fast_carrier(fcn, n1) * inv;
    r.z = fast_env(bc * n2) * fast_carrier(fcn, n2) * inv;
    r.w = fast_env(bc * n3) * fast_carrier(fcn, n3) * inv;
  }
  __builtin_nontemporal_store(r, &((vf4*)out)[blk * 256 + tid]);
}

// ---------------------------------------------------------------------------
extern "C" void kernel_launch(void* const* d_in, const int* in_sizes, int n_in,
                              void* d_out, int out_size, void* d_ws, size_t ws_size,
                              hipStream_t stream) {
  const float* Q  = (const float*)d_in[0];   // [64, 512] f32
  const float* fc = (const float*)d_in[1];   // [512] f32
  float* out      = (float*)d_out;           // [64, 512, 1024] f32
  float* ws       = (float*)d_ws;            // [512*64] per-signal |X|^2 max

  k_maxfft<<<64 * 512 / 4, 256, 0, stream>>>(Q, fc, ws);
  k_write <<<64 * 512,     256, 0, stream>>>(Q, fc, ws, out);
}